// Round 1
// baseline (96.571 us; speedup 1.0000x reference)
//
#include <hip/hip_runtime.h>
#include <hip/hip_bf16.h>

// Problem constants (from reference): B=4, D=64, K=32, N = T*H*W = 8*32*32 = 8192
#define BB 4
#define DD 64
#define KK 32
#define NN 8192
#define LOG2E 1.4426950408889634f

// Kernel 1: per (b,d) block-column of 1024 n's (4 per thread).
// Computes E[b,d,n] = sum_k softmax_k(scale*resid^2) * resid  and accumulates
// sum_n E into eglob[b*D+d] via one atomicAdd per block.
// NOTE: softmax args are all <= 0 (scale in [-1,0), resid^2 >= 0) and bounded
// ~>= -30, so single-pass exp without max-subtraction is numerically safe.
__global__ __launch_bounds__(256) void enc_kernel(
    const float* __restrict__ X,        // [B, D, N]
    const float* __restrict__ cw,       // [K, D]
    const float* __restrict__ sc,       // [K, D]
    float* __restrict__ E,              // [B, D, N]  (= d_out, staging)
    float* __restrict__ eglob)          // [B*D], pre-zeroed
{
    const int bd   = blockIdx.x >> 3;         // 256 (b,d) pairs, 8 chunks each
    const int nblk = blockIdx.x & 7;
    const int d    = bd & (DD - 1);
    const int n    = nblk * 1024 + (threadIdx.x << 2);
    const int idx  = bd * NN + n;

    const float4 x = *(const float4*)(X + idx);

    float num0 = 0.f, num1 = 0.f, num2 = 0.f, num3 = 0.f;
    float den0 = 0.f, den1 = 0.f, den2 = 0.f, den3 = 0.f;

#pragma unroll
    for (int k = 0; k < KK; ++k) {
        const float c = cw[k * DD + d];               // wave-uniform -> s_load
        const float s = sc[k * DD + d] * LOG2E;       // fold log2(e): exp(x)=exp2(x*log2e)
        const float r0 = x.x - c;
        const float r1 = x.y - c;
        const float r2 = x.z - c;
        const float r3 = x.w - c;
        const float e0 = exp2f(s * r0 * r0);          // v_exp_f32 (exp2 is native)
        const float e1 = exp2f(s * r1 * r1);
        const float e2 = exp2f(s * r2 * r2);
        const float e3 = exp2f(s * r3 * r3);
        den0 += e0; num0 = fmaf(e0, r0, num0);
        den1 += e1; num1 = fmaf(e1, r1, num1);
        den2 += e2; num2 = fmaf(e2, r2, num2);
        den3 += e3; num3 = fmaf(e3, r3, num3);
    }

    float4 out;
    out.x = num0 / den0;
    out.y = num1 / den1;
    out.z = num2 / den2;
    out.w = num3 / den3;
    *(float4*)(E + idx) = out;

    // block reduction of sum_n E for the global pool
    float t = out.x + out.y + out.z + out.w;
#pragma unroll
    for (int off = 32; off > 0; off >>= 1)
        t += __shfl_down(t, off);                     // width = wave = 64

    __shared__ float smem[4];
    const int lane = threadIdx.x & 63;
    const int wv   = threadIdx.x >> 6;
    if (lane == 0) smem[wv] = t;
    __syncthreads();
    if (threadIdx.x == 0) {
        const float bs = smem[0] + smem[1] + smem[2] + smem[3];
        atomicAdd(&eglob[bd], bs);
    }
}

// Kernel 2: gamma[b,d] = sigmoid( (1/K) * sum_j eglob[b,j] * fc_w[d,j] + fc_b[d] )
__global__ __launch_bounds__(256) void gamma_kernel(
    const float* __restrict__ eglob,    // [B*D] (raw sums over n and k)
    const float* __restrict__ fcw,      // [D, D]
    const float* __restrict__ fcb,      // [D]
    float* __restrict__ gamma)          // [B*D]
{
    const int bd = threadIdx.x;         // 256 = B*D
    const int b  = bd >> 6;
    const int d  = bd & (DD - 1);
    float acc = fcb[d];
    const float invK = 1.0f / (float)KK;
#pragma unroll
    for (int j = 0; j < DD; ++j)
        acc = fmaf(eglob[b * DD + j] * invK, fcw[d * DD + j], acc);
    gamma[bd] = 1.0f / (1.0f + __expf(-acc));
}

// Kernel 3: out = relu(E * (1 + gamma[b,d])), in place on d_out.
__global__ __launch_bounds__(256) void out_kernel(
    float* __restrict__ E,              // [B, D, N] in/out (= d_out)
    const float* __restrict__ gamma)    // [B*D]
{
    const int bd  = blockIdx.x >> 3;
    const int idx = bd * NN + (blockIdx.x & 7) * 1024 + (threadIdx.x << 2);
    const float g = 1.0f + gamma[bd];   // wave-uniform -> s_load
    float4 e = *(float4*)(E + idx);
    e.x = fmaxf(e.x * g, 0.f);
    e.y = fmaxf(e.y * g, 0.f);
    e.z = fmaxf(e.z * g, 0.f);
    e.w = fmaxf(e.w * g, 0.f);
    *(float4*)(E + idx) = e;
}

extern "C" void kernel_launch(void* const* d_in, const int* in_sizes, int n_in,
                              void* d_out, int out_size, void* d_ws, size_t ws_size,
                              hipStream_t stream) {
    const float* X   = (const float*)d_in[0];   // [B, D, T, H, W]
    const float* cw  = (const float*)d_in[1];   // [K, D]
    const float* sc  = (const float*)d_in[2];   // [K, D]
    const float* fcw = (const float*)d_in[3];   // [D, D]
    const float* fcb = (const float*)d_in[4];   // [D]
    float* out = (float*)d_out;                 // [B, D, T, H, W]

    float* eglob = (float*)d_ws;                // [B*D]
    float* gamma = eglob + BB * DD;             // [B*D]

    // ws is re-poisoned to 0xAA before every call -> zero the accumulator.
    hipMemsetAsync(eglob, 0, BB * DD * sizeof(float), stream);

    const int grid = BB * DD * (NN / 1024);     // 2048 blocks
    enc_kernel<<<grid, 256, 0, stream>>>(X, cw, sc, out, eglob);
    gamma_kernel<<<1, 256, 0, stream>>>(eglob, fcw, fcb, gamma);
    out_kernel<<<grid, 256, 0, stream>>>(out, gamma);
}

// Round 2
// 90.482 us; speedup vs baseline: 1.0673x; 1.0673x over previous
//
#include <hip/hip_runtime.h>
#include <hip/hip_bf16.h>

// Problem constants: B=4, D=64, K=32, N = T*H*W = 8192
#define BB 4
#define DD 64
#define KK 32
#define NN 8192
#define LOG2E 1.4426950408889634f

// Kernel 1: per (b,d) column chunk of 1024 n's (4/thread, float4).
// E[b,d,n] = sum_k softmax_k(scale*(x-c)^2) * (x-c); also block-reduces
// sum_n E into partial[blockIdx.x] (private slot -> no memset, no atomics).
// Softmax args are all <= 0 and bounded (scale in [-1,0)), so single-pass
// exp2 without max-subtraction is safe.
__global__ __launch_bounds__(256) void enc_kernel(
    const float* __restrict__ X,        // [B, D, N]
    const float* __restrict__ cw,       // [K, D]
    const float* __restrict__ sc,       // [K, D]
    float* __restrict__ E,              // [B, D, N]  (= d_out, staging)
    float* __restrict__ partial)        // [2048] per-block sums
{
    const int bd   = blockIdx.x >> 3;         // (b,d) pair; 8 chunks each
    const int d    = bd & (DD - 1);
    const int idx  = bd * NN + (blockIdx.x & 7) * 1024 + (threadIdx.x << 2);

    const float4 x = *(const float4*)(X + idx);

    float num0 = 0.f, num1 = 0.f, num2 = 0.f, num3 = 0.f;
    float den0 = 0.f, den1 = 0.f, den2 = 0.f, den3 = 0.f;

#pragma unroll
    for (int k = 0; k < KK; ++k) {
        const float c = cw[k * DD + d];               // wave-uniform -> s_load
        const float s = sc[k * DD + d] * LOG2E;       // exp(x) = exp2(x*log2e)
        const float r0 = x.x - c;
        const float r1 = x.y - c;
        const float r2 = x.z - c;
        const float r3 = x.w - c;
        const float e0 = exp2f(s * r0 * r0);          // native v_exp_f32
        const float e1 = exp2f(s * r1 * r1);
        const float e2 = exp2f(s * r2 * r2);
        const float e3 = exp2f(s * r3 * r3);
        den0 += e0; num0 = fmaf(e0, r0, num0);
        den1 += e1; num1 = fmaf(e1, r1, num1);
        den2 += e2; num2 = fmaf(e2, r2, num2);
        den3 += e3; num3 = fmaf(e3, r3, num3);
    }

    float4 out;
    out.x = num0 / den0;
    out.y = num1 / den1;
    out.z = num2 / den2;
    out.w = num3 / den3;
    *(float4*)(E + idx) = out;

    // block-reduce sum_n E -> private partial slot (no atomics needed)
    float t = out.x + out.y + out.z + out.w;
#pragma unroll
    for (int off = 32; off > 0; off >>= 1)
        t += __shfl_down(t, off);                     // wave = 64

    __shared__ float smem[4];
    if ((threadIdx.x & 63) == 0) smem[threadIdx.x >> 6] = t;
    __syncthreads();
    if (threadIdx.x == 0)
        partial[blockIdx.x] = smem[0] + smem[1] + smem[2] + smem[3];
}

// Kernel 2: each block reduces the 512 partials of its batch b into
// eglob[b,:], computes gamma(b,d) redundantly (64 FMAs), then applies
// relu(E * (1+gamma)) in place over its 1024-element chunk.
__global__ __launch_bounds__(256) void gate_kernel(
    float* __restrict__ E,              // [B, D, N] in/out (= d_out)
    const float* __restrict__ partial,  // [2048]: partial[(b*64+j)*8 + c]
    const float* __restrict__ fcw,      // [D, D]
    const float* __restrict__ fcb)      // [D]
{
    const int bd  = blockIdx.x >> 3;
    const int b   = bd >> 6;
    const int d   = bd & (DD - 1);
    const int idx = bd * NN + (blockIdx.x & 7) * 1024 + (threadIdx.x << 2);

    __shared__ float eg[DD];
    if (threadIdx.x < DD) {
        // 8 contiguous partials per (b,j): two dwordx4 loads
        const float4* p = (const float4*)(partial + b * 512 + threadIdx.x * 8);
        const float4 a = p[0], c4 = p[1];
        eg[threadIdx.x] = (a.x + a.y + a.z + a.w) + (c4.x + c4.y + c4.z + c4.w);
    }
    // independent: start the E load before the barrier
    float4 e = *(float4*)(E + idx);
    __syncthreads();

    float acc = 0.f;
#pragma unroll
    for (int j = 0; j < DD; ++j)
        acc = fmaf(eg[j], fcw[d * DD + j], acc);      // eg[j]: LDS broadcast; fcw: s_load
    const float z = acc * (1.0f / (float)KK) + fcb[d];
    const float g = 1.0f + 1.0f / (1.0f + exp2f(-z * LOG2E));   // 1 + sigmoid(z)

    e.x = fmaxf(e.x * g, 0.f);
    e.y = fmaxf(e.y * g, 0.f);
    e.z = fmaxf(e.z * g, 0.f);
    e.w = fmaxf(e.w * g, 0.f);
    *(float4*)(E + idx) = e;
}

extern "C" void kernel_launch(void* const* d_in, const int* in_sizes, int n_in,
                              void* d_out, int out_size, void* d_ws, size_t ws_size,
                              hipStream_t stream) {
    const float* X   = (const float*)d_in[0];   // [B, D, T, H, W]
    const float* cw  = (const float*)d_in[1];   // [K, D]
    const float* sc  = (const float*)d_in[2];   // [K, D]
    const float* fcw = (const float*)d_in[3];   // [D, D]
    const float* fcb = (const float*)d_in[4];   // [D]
    float* out = (float*)d_out;                 // [B, D, T, H, W]

    float* partial = (float*)d_ws;              // [2048], every slot written by K1

    const int grid = BB * DD * (NN / 1024);     // 2048 blocks
    enc_kernel<<<grid, 256, 0, stream>>>(X, cw, sc, out, partial);
    gate_kernel<<<grid, 256, 0, stream>>>(out, partial, fcw, fcb);
}